// Round 10
// baseline (279.446 us; speedup 1.0000x reference)
//
#include <hip/hip_runtime.h>
#include <hip/hip_fp16.h>

#define N_NODES 40000
#define N_EDGES 640000
#define NFEAT   128
#define N_GRAPHS 512
#define SCAN_NB 157        // ceil(40000/256)
#define NBKT    157        // col buckets of 256 cols
#define BKT_CAP 8192       // slots per bucket region (mean ~4076, safe)
#define BIN_BLK_EDGES 2048
#define NBLK_A ((N_EDGES + BIN_BLK_EDGES - 1) / BIN_BLK_EDGES)  // 313
#define EPAD_MAX (N_EDGES + 3 * N_NODES)   // worst-case padded CSR

typedef _Float16 half8 __attribute__((ext_vector_type(8)));
typedef float    floatx4 __attribute__((ext_vector_type(4)));

// ===========================================================================
// Init: gcursor=0, gcnt=0, out=bfc, hbuf sentinel row=0
// ===========================================================================
__global__ void init_misc_kernel(int* __restrict__ gcursor, int* __restrict__ gcnt,
                                 float* __restrict__ out, const float* __restrict__ bfc,
                                 __half* __restrict__ hsent) {
    int t = threadIdx.x;
    if (t < NBKT) gcursor[t] = 0;
    float b = bfc[0];
    for (int i = t; i < N_GRAPHS; i += 256) { gcnt[i] = 0; out[i] = b; }
    if (t < NFEAT) hsent[t] = __float2half(0.0f);
}

__global__ void batch_hist_kernel(const int* __restrict__ batch, int* __restrict__ gcnt, int n) {
    int i = blockIdx.x * blockDim.x + threadIdx.x;
    if (i < n) atomicAdd(&gcnt[batch[i]], 1);
}

// ===========================================================================
// Pass A: bin edges into NBKT coarse buckets (col>>8), packed (collow<<16|row).
// ===========================================================================
__global__ __launch_bounds__(256) void bin_kernel(const int* __restrict__ ei,
                                                  int* __restrict__ gcursor,
                                                  unsigned int* __restrict__ binned) {
    __shared__ int lhist[NBKT];
    __shared__ int lbase[NBKT];
    const int t  = threadIdx.x;
    const int e0 = blockIdx.x * BIN_BLK_EDGES;

    if (t < NBKT) lhist[t] = 0;
    __syncthreads();

    int creg[BIN_BLK_EDGES / 256];
    #pragma unroll
    for (int i = 0; i < BIN_BLK_EDGES / 256; ++i) {
        int e = e0 + i * 256 + t;
        creg[i] = (e < N_EDGES) ? ei[N_EDGES + e] : -1;
        if (creg[i] >= 0) atomicAdd(&lhist[creg[i] >> 8], 1);
    }
    __syncthreads();

    if (t < NBKT) { lbase[t] = atomicAdd(&gcursor[t], lhist[t]); lhist[t] = 0; }
    __syncthreads();

    #pragma unroll
    for (int i = 0; i < BIN_BLK_EDGES / 256; ++i) {
        int c = creg[i];
        if (c >= 0) {
            int e = e0 + i * 256 + t;
            int r = ei[e];
            int bkt = c >> 8;
            int slot = atomicAdd(&lhist[bkt], 1);
            binned[(size_t)bkt * BKT_CAP + lbase[bkt] + slot] =
                (unsigned int)r | ((unsigned int)(c & 255) << 16);
        }
    }
}

// ===========================================================================
// Pass B: per-bucket col histogram -> dinv, local exclusive scan of padded
// degrees -> rowptr local offsets + bucket totals.
// ===========================================================================
__global__ __launch_bounds__(256) void bucket_hist_kernel(const unsigned int* __restrict__ binned,
                                                          const int* __restrict__ gcursor,
                                                          float* __restrict__ dinv,
                                                          int* __restrict__ rowptr,
                                                          int* __restrict__ bsums) {
    __shared__ int chist[256];
    __shared__ int scn[256];
    const int b = blockIdx.x, t = threadIdx.x;
    chist[t] = 0;
    __syncthreads();
    const int cnt = gcursor[b];
    const unsigned int* src = binned + (size_t)b * BKT_CAP;
    for (int i = t; i < cnt; i += 256) atomicAdd(&chist[src[i] >> 16], 1);
    __syncthreads();
    const int col = b * 256 + t;
    const int valid = (col < N_NODES);
    int d = chist[t];
    if (valid) dinv[col] = rsqrtf(1.0f + (float)d);
    int pd = valid ? ((d + 3) & ~3) : 0;
    scn[t] = pd;
    __syncthreads();
    for (int off = 1; off < 256; off <<= 1) {
        int add = (t >= off) ? scn[t - off] : 0;
        __syncthreads();
        scn[t] += add;
        __syncthreads();
    }
    if (valid) rowptr[col] = scn[t] - pd;   // local offset
    if (t == 255) bsums[b] = scn[255];      // bucket total
}

// 157-element exclusive scan of bucket totals; write rowptr[N] = grand total
__global__ void scan157_kernel(int* __restrict__ bsums, int* __restrict__ rowptr) {
    __shared__ int tmp[256];
    int t = threadIdx.x;
    int v = (t < NBKT) ? bsums[t] : 0;
    tmp[t] = v;
    __syncthreads();
    for (int off = 1; off < 256; off <<= 1) {
        int add = (t >= off) ? tmp[t - off] : 0;
        __syncthreads();
        tmp[t] += add;
        __syncthreads();
    }
    if (t < NBKT) bsums[t] = tmp[t] - v;
    if (t == 255) rowptr[N_NODES] = tmp[255];
}

// ===========================================================================
// Pass C: finalize rowptr (+base), scatter into CSR via LDS cursors, pads.
// ===========================================================================
template <typename IdxT>
__global__ __launch_bounds__(256) void bucket_scatter_kernel(const unsigned int* __restrict__ binned,
                                                             const int* __restrict__ gcursor,
                                                             const int* __restrict__ bsums,
                                                             int* __restrict__ rowptr,
                                                             IdxT* __restrict__ csr) {
    __shared__ int ccur[256];
    const int b = blockIdx.x, t = threadIdx.x;
    const int col = b * 256 + t;
    const int base = bsums[b];
    int startp = 0;
    if (col < N_NODES) {
        startp = rowptr[col] + base;
        rowptr[col] = startp;     // final
    }
    ccur[t] = startp;
    __syncthreads();
    const int cnt = gcursor[b];
    const unsigned int* src = binned + (size_t)b * BKT_CAP;
    for (int i = t; i < cnt; i += 256) {
        unsigned int u = src[i];
        int slot = atomicAdd(&ccur[u >> 16], 1);
        csr[slot] = (IdxT)(u & 0xFFFFu);
    }
    __syncthreads();
    if (col < N_NODES) {
        int cur = ccur[t];
        int deg = cur - startp;
        int endp = startp + ((deg + 3) & ~3);
        for (int p = cur; p < endp; ++p) csr[p] = (IdxT)N_NODES;
    }
}

// ===========================================================================
// MFMA GEMM: Ht[r][c] = dinv[r] * sum_k X[r][k] * W[k][c]   (fp16 out)
// v_mfma_f32_16x16x32_f16. Block = 512 thr = 8 waves; wave w owns col-tile
// n0=16w; block covers 64 rows x 128 cols; grid = 40000/64 = 625 (exact).
// Layouts (verified, guide §3 m89/m92/m120):
//   A[m=lane&15][k=quad*8+j]   B[k=quad*8+j][n=lane&15]
//   C/D: col=lane&15, row=quad*4+reg
// B-frags loaded once per wave from global W (64 KB, L2-resident), fp32->fp16
// cvt in-register. No LDS, no barrier. InT = float (both layers; fp32 obuf).
// ===========================================================================
template <typename InT>
__global__ __launch_bounds__(512) void gemm_mfma_kernel(const InT* __restrict__ X,
                                                        const float* __restrict__ W,
                                                        const float* __restrict__ dinv,
                                                        __half* __restrict__ H) {
    const int wave = threadIdx.x >> 6;     // 0..7 -> col tile
    const int lane = threadIdx.x & 63;
    const int quad = lane >> 4;            // 0..3
    const int l16  = lane & 15;
    const int n0   = wave * 16;
    const int row0 = blockIdx.x * 64;

    // B fragments: b[kc][j] = W[kc*32 + quad*8 + j][n0 + l16]
    half8 bfrag[4];
    #pragma unroll
    for (int kc = 0; kc < 4; ++kc) {
        #pragma unroll
        for (int j = 0; j < 8; ++j) {
            int k = kc * 32 + quad * 8 + j;
            bfrag[kc][j] = (_Float16)W[k * NFEAT + n0 + l16];
        }
    }

    #pragma unroll
    for (int rt = 0; rt < 4; ++rt) {
        const int arow = row0 + rt * 16 + l16;
        const InT* xr = X + (size_t)arow * NFEAT;

        half8 afrag[4];
        #pragma unroll
        for (int kc = 0; kc < 4; ++kc) {
            if constexpr (sizeof(InT) == 4) {
                const float* p = (const float*)xr + kc * 32 + quad * 8;
                float4 f0 = *(const float4*)p;
                float4 f1 = *(const float4*)(p + 4);
                afrag[kc][0] = (_Float16)f0.x;
                afrag[kc][1] = (_Float16)f0.y;
                afrag[kc][2] = (_Float16)f0.z;
                afrag[kc][3] = (_Float16)f0.w;
                afrag[kc][4] = (_Float16)f1.x;
                afrag[kc][5] = (_Float16)f1.y;
                afrag[kc][6] = (_Float16)f1.z;
                afrag[kc][7] = (_Float16)f1.w;
            } else {
                afrag[kc] = *(const half8*)((const __half*)xr + kc * 32 + quad * 8);
            }
        }

        floatx4 acc = {0.0f, 0.0f, 0.0f, 0.0f};
        #pragma unroll
        for (int kc = 0; kc < 4; ++kc)
            acc = __builtin_amdgcn_mfma_f32_16x16x32_f16(afrag[kc], bfrag[kc], acc, 0, 0, 0);

        // D: lane holds rows rt*16 + quad*4 + r, col n0 + l16
        #pragma unroll
        for (int r = 0; r < 4; ++r) {
            int orow = row0 + rt * 16 + quad * 4 + r;
            float dr = dinv[orow];
            H[(size_t)orow * NFEAT + n0 + l16] = __float2half(acc[r] * dr);
        }
    }
}

// ===========================================================================
// fp16 gather (r9 shape, idx prefetch): one wave per node; 8 B/lane;
// half-waves take alternating neighbors; padded CSR -> aligned 4-index loads,
// next idx vector prefetched. NO dynamic vector indexing (r8 LDS-spill trap).
// FUSE_POOL: dot with Wfc, wave-reduce, plain store nodedot[node].
// ===========================================================================
__device__ inline float4 load_h4(const __half* p) {
    uint2 raw = *(const uint2*)p;
    __half2 h0 = *(__half2*)&raw.x;
    __half2 h1 = *(__half2*)&raw.y;
    float2 f0 = __half22float2(h0);
    float2 f1 = __half22float2(h1);
    return make_float4(f0.x, f0.y, f1.x, f1.y);
}

template <typename IdxT, typename IdxV, bool FUSE_POOL>
__global__ __launch_bounds__(256) void gather_h16_kernel(
        const int* __restrict__ rowptr, const IdxT* __restrict__ csr,
        const float* __restrict__ dinv, const __half* __restrict__ Ht,
        const float* __restrict__ bias, float* __restrict__ out,
        const float* __restrict__ Wfc, float* __restrict__ nodedot, int n) {
    int gid  = blockIdx.x * blockDim.x + threadIdx.x;
    int node = gid >> 6;
    if (node >= n) return;
    int lane = threadIdx.x & 63;
    int half = lane >> 5;
    int f4   = (lane & 31) * 4;

    int start = rowptr[node];
    int end   = rowptr[node + 1];

    float4 a0 = {0.f, 0.f, 0.f, 0.f};
    float4 a1 = {0.f, 0.f, 0.f, 0.f};
    if (half == 0) a0 = load_h4(Ht + (size_t)node * NFEAT + f4);  // self-loop

    IdxV nxt = *(const IdxV*)(csr + start);
    for (int j = start; j < end; j += 4) {
        IdxV cur = nxt;
        int jn = j + 4;
        if (jn < end) nxt = *(const IdxV*)(csr + jn);
        int r0 = half ? (int)cur.z : (int)cur.x;
        int r1 = half ? (int)cur.w : (int)cur.y;
        float4 v0 = load_h4(Ht + (size_t)r0 * NFEAT + f4);
        float4 v1 = load_h4(Ht + (size_t)r1 * NFEAT + f4);
        a0.x += v0.x; a0.y += v0.y; a0.z += v0.z; a0.w += v0.w;
        a1.x += v1.x; a1.y += v1.y; a1.z += v1.z; a1.w += v1.w;
    }
    a0.x += a1.x; a0.y += a1.y; a0.z += a1.z; a0.w += a1.w;

    a0.x += __shfl_xor(a0.x, 32, 64);
    a0.y += __shfl_xor(a0.y, 32, 64);
    a0.z += __shfl_xor(a0.z, 32, 64);
    a0.w += __shfl_xor(a0.w, 32, 64);

    if (half == 0) {
        float di  = dinv[node];
        float4 bb = *(const float4*)(bias + f4);
        float4 o;
        o.x = fmaxf(a0.x * di + bb.x, 0.0f);
        o.y = fmaxf(a0.y * di + bb.y, 0.0f);
        o.z = fmaxf(a0.z * di + bb.z, 0.0f);
        o.w = fmaxf(a0.w * di + bb.w, 0.0f);
        if (!FUSE_POOL) {
            *(float4*)(out + (size_t)node * NFEAT + f4) = o;
        } else {
            float4 wf = *(const float4*)(Wfc + f4);
            float d = o.x * wf.x + o.y * wf.y + o.z * wf.z + o.w * wf.w;
            d += __shfl_xor(d, 1, 64);
            d += __shfl_xor(d, 2, 64);
            d += __shfl_xor(d, 4, 64);
            d += __shfl_xor(d, 8, 64);
            d += __shfl_xor(d, 16, 64);
            if (lane == 0) nodedot[node] = d;   // wave owns node: plain store
        }
    }
}

// out[batch[i]] += nodedot[i] / cnt
__global__ void pool_final_kernel(const float* __restrict__ nodedot,
                                  const int* __restrict__ batch,
                                  const int* __restrict__ gcnt,
                                  float* __restrict__ out, int n) {
    int i = blockIdx.x * blockDim.x + threadIdx.x;
    if (i < n) {
        int g = batch[i];
        int c = gcnt[g];
        float cf = (float)(c > 0 ? c : 1);
        atomicAdd(&out[g], nodedot[i] / cf);
    }
}

// ===========================================================================
// Tier C fallback kernels (fp32, atomic scatter)
// ===========================================================================
__global__ void edge_deg_int_kernel(const int* __restrict__ ei, int* __restrict__ degcnt, int E) {
    int e = blockIdx.x * blockDim.x + threadIdx.x;
    if (e < E) atomicAdd(&degcnt[ei[E + e]], 1);
}

__global__ void dinv_from_int_kernel(const int* __restrict__ degcnt, float* __restrict__ dinv, int n) {
    int i = blockIdx.x * blockDim.x + threadIdx.x;
    if (i < n) dinv[i] = rsqrtf(1.0f + (float)degcnt[i]);
}

__global__ __launch_bounds__(256, 4) void gemm64f_kernel(const float* __restrict__ X,
                                                         const float* __restrict__ W,
                                                         const float* __restrict__ dinv,
                                                         float* __restrict__ H) {
    __shared__ float Ws[128 * 64];
    const int colhalf = blockIdx.x & 1;
    const int tile    = blockIdx.x >> 1;
    for (int i = threadIdx.x; i < 2048; i += 256) {
        int k   = i >> 4;
        int cc4 = (i & 15) * 4;
        *(float4*)(Ws + k * 64 + cc4) = *(const float4*)(W + k * 128 + colhalf * 64 + cc4);
    }
    __syncthreads();
    const int rg = threadIdx.x >> 4;
    const int cg = threadIdx.x & 15;
    const int row0 = tile * 64 + rg * 4;
    const float* x0 = X + (size_t)row0 * NFEAT;
    float acc[4][4] = {};
    #pragma unroll 4
    for (int k = 0; k < 128; k += 4) {
        float4 xv[4];
        float4 wv[4];
        #pragma unroll
        for (int i = 0; i < 4; i++) xv[i] = *(const float4*)(x0 + (size_t)i * NFEAT + k);
        #pragma unroll
        for (int m = 0; m < 4; m++) wv[m] = *(const float4*)(Ws + (k + m) * 64 + cg * 4);
        #pragma unroll
        for (int i = 0; i < 4; i++) {
            const float xi[4] = {xv[i].x, xv[i].y, xv[i].z, xv[i].w};
            #pragma unroll
            for (int m = 0; m < 4; m++) {
                acc[i][0] += xi[m] * wv[m].x;
                acc[i][1] += xi[m] * wv[m].y;
                acc[i][2] += xi[m] * wv[m].z;
                acc[i][3] += xi[m] * wv[m].w;
            }
        }
    }
    #pragma unroll
    for (int i = 0; i < 4; i++) {
        float dr = dinv[row0 + i];
        float4 o = {acc[i][0] * dr, acc[i][1] * dr, acc[i][2] * dr, acc[i][3] * dr};
        *(float4*)(H + (size_t)(row0 + i) * NFEAT + cg * 4 + colhalf * 64) = o;
    }
}

__global__ __launch_bounds__(256) void edge_scatter_kernel(const int* __restrict__ ei,
                                                           const float* __restrict__ dinv,
                                                           const float* __restrict__ H,
                                                           float* __restrict__ agg,
                                                           int E) {
    long long gid = (long long)blockIdx.x * blockDim.x + threadIdx.x;
    int e = (int)(gid >> 5);
    if (e >= E) return;
    int c4 = ((int)gid & 31) * 4;
    int r = ei[e];
    int c = ei[E + e];
    float norm = dinv[c];
    const float4 hv = *(const float4*)(H + (size_t)r * NFEAT + c4);
    float* dst = agg + (size_t)c * NFEAT + c4;
    atomicAdd(dst + 0, hv.x * norm);
    atomicAdd(dst + 1, hv.y * norm);
    atomicAdd(dst + 2, hv.z * norm);
    atomicAdd(dst + 3, hv.w * norm);
}

__global__ void post_kernel(float* __restrict__ agg, const float* __restrict__ H,
                            const float* __restrict__ dinv, const float* __restrict__ b,
                            int n) {
    int gid = blockIdx.x * blockDim.x + threadIdx.x;
    if (gid >= n * 32) return;
    int node = gid >> 5;
    int c4 = (gid & 31) * 4;
    float s = dinv[node];
    float4 a  = *(float4*)(agg + (size_t)gid * 4);
    float4 hv = *(const float4*)(H + (size_t)gid * 4);
    float4 bb = *(const float4*)(b + c4);
    float4 o;
    o.x = fmaxf(a.x + hv.x * s + bb.x, 0.0f);
    o.y = fmaxf(a.y + hv.y * s + bb.y, 0.0f);
    o.z = fmaxf(a.z + hv.z * s + bb.z, 0.0f);
    o.w = fmaxf(a.w + hv.w * s + bb.w, 0.0f);
    *(float4*)(agg + (size_t)gid * 4) = o;
}

__global__ __launch_bounds__(128) void pool_fc_kernel(const float* __restrict__ H,
                                                      const int* __restrict__ batch,
                                                      const float* __restrict__ Wfc,
                                                      const float* __restrict__ bfc,
                                                      float* __restrict__ out, int n) {
    int g = blockIdx.x;
    int tid = threadIdx.x;
    int lo = 0, hi = n;
    while (lo < hi) { int mid = (lo + hi) >> 1; if (batch[mid] < g) lo = mid + 1; else hi = mid; }
    int start = lo;
    hi = n;
    while (lo < hi) { int mid = (lo + hi) >> 1; if (batch[mid] < g + 1) lo = mid + 1; else hi = mid; }
    int end = lo;
    float acc = 0.0f;
    for (int nd = start; nd < end; ++nd) acc += H[(size_t)nd * NFEAT + tid];
    float cnt = (float)((end - start) > 0 ? (end - start) : 1);
    float v = (acc / cnt) * Wfc[tid];
    __shared__ float red[128];
    red[tid] = v;
    __syncthreads();
    #pragma unroll
    for (int s = 64; s > 0; s >>= 1) {
        if (tid < s) red[tid] += red[tid + s];
        __syncthreads();
    }
    if (tid == 0) out[g] = red[0] + bfc[0];
}

// ===========================================================================
// Host launcher
// ===========================================================================
template <typename IdxT, typename IdxV>
static void run_csr_path(const float* x, const int* ei, const int* batch,
                         const float* W1, const float* b1, const float* W2,
                         const float* b2, const float* Wfc, const float* bfc,
                         float* out, void* d_ws, hipStream_t stream) {
    char* ws = (char*)d_ws;
    const size_t hbytes = (size_t)(N_NODES + 1) * NFEAT * sizeof(__half);  // +1 sentinel row
    const size_t obytes = (size_t)N_NODES * NFEAT * sizeof(float);
    __half* hbuf  = (__half*)ws;
    float*  obuf  = (float*)(ws + hbytes);
    IdxT*   csr   = (IdxT*)(ws + hbytes + obytes);
    char*   p     = ws + hbytes + obytes + ((size_t)EPAD_MAX * sizeof(IdxT) + 15) / 16 * 16;
    int*    rowptr = (int*)p;                p += ((size_t)(N_NODES + 1) * 4 + 15) / 16 * 16;
    float*  dinv   = (float*)p;              p += ((size_t)N_NODES * 4 + 15) / 16 * 16;
    int*    gcnt   = (int*)p;                // 512 ints (live through pool_final)

    // CSR-build scratch overlapping obuf (dead until gather1 writes it)
    unsigned int* binned = (unsigned int*)obuf;        // NBKT*BKT_CAP u32 = 5.14 MB
    int* bsums   = (int*)obuf + NBKT * BKT_CAP;        // NBKT ints
    int* gcursor = bsums + NBKT;                       // NBKT ints
    // nodedot overlaps obuf head (obuf dead after gemm2 reads it; plain stores)
    float* nodedot = (float*)obuf;

    // ---- init + CSR build (binned counting sort, fused scans) ----
    init_misc_kernel<<<1, 256, 0, stream>>>(gcursor, gcnt, out, bfc,
                                            hbuf + (size_t)N_NODES * NFEAT);
    batch_hist_kernel<<<SCAN_NB, 256, 0, stream>>>(batch, gcnt, N_NODES);
    bin_kernel<<<NBLK_A, 256, 0, stream>>>(ei, gcursor, binned);
    bucket_hist_kernel<<<NBKT, 256, 0, stream>>>(binned, gcursor, dinv, rowptr, bsums);
    scan157_kernel<<<1, 256, 0, stream>>>(bsums, rowptr);
    bucket_scatter_kernel<IdxT><<<NBKT, 256, 0, stream>>>(binned, gcursor, bsums, rowptr, csr);

    // ---- layer 1 ----
    gemm_mfma_kernel<float><<<N_NODES / 64, 512, 0, stream>>>(x, W1, dinv, hbuf);
    gather_h16_kernel<IdxT, IdxV, false><<<(N_NODES * 64) / 256, 256, 0, stream>>>(
        rowptr, csr, dinv, hbuf, b1, obuf, nullptr, nullptr, N_NODES);

    // ---- layer 2 ----
    gemm_mfma_kernel<float><<<N_NODES / 64, 512, 0, stream>>>(obuf, W2, dinv, hbuf);
    gather_h16_kernel<IdxT, IdxV, true><<<(N_NODES * 64) / 256, 256, 0, stream>>>(
        rowptr, csr, dinv, hbuf, b2, nullptr, Wfc, nodedot, N_NODES);

    // ---- final pool ----
    pool_final_kernel<<<SCAN_NB, 256, 0, stream>>>(nodedot, batch, gcnt, out, N_NODES);
}

extern "C" void kernel_launch(void* const* d_in, const int* in_sizes, int n_in,
                              void* d_out, int out_size, void* d_ws, size_t ws_size,
                              hipStream_t stream) {
    const float* x     = (const float*)d_in[0];
    const int*   ei    = (const int*)  d_in[1];
    const int*   batch = (const int*)  d_in[2];
    const float* W1    = (const float*)d_in[3];
    const float* b1    = (const float*)d_in[4];
    const float* W2    = (const float*)d_in[5];
    const float* b2    = (const float*)d_in[6];
    const float* Wfc   = (const float*)d_in[7];
    const float* bfc   = (const float*)d_in[8];
    float* out = (float*)d_out;

    const size_t hbytes = (size_t)(N_NODES + 1) * NFEAT * sizeof(__half);
    const size_t obytes = (size_t)N_NODES * NFEAT * sizeof(float);
    const size_t tail   = ((size_t)(N_NODES + 1) * 4 + 15) / 16 * 16
                        + ((size_t)N_NODES * 4 + 15) / 16 * 16
                        + (size_t)N_GRAPHS * 4;
    const size_t needA = hbytes + obytes + ((size_t)EPAD_MAX * 4 + 15) / 16 * 16 + tail;
    const size_t needB = hbytes + obytes + ((size_t)EPAD_MAX * 2 + 15) / 16 * 16 + tail;

    if (ws_size >= needA) {
        run_csr_path<int, int4>(x, ei, batch, W1, b1, W2, b2, Wfc, bfc, out, d_ws, stream);
    } else if (ws_size >= needB) {
        run_csr_path<unsigned short, ushort4>(x, ei, batch, W1, b1, W2, b2, Wfc, bfc, out, d_ws, stream);
    } else {
        // Tier C: fp32 atomic-scatter fallback
        float* ws   = (float*)d_ws;
        int*   degc = (int*)ws;
        float* dinv = ws + N_NODES;
        float* hbuf = ws + 2 * N_NODES;
        float* agg  = hbuf + (size_t)N_NODES * NFEAT;
        const size_t fb2 = (size_t)N_NODES * NFEAT * sizeof(float);

        hipMemsetAsync(degc, 0, (size_t)N_NODES * sizeof(int), stream);
        edge_deg_int_kernel<<<N_EDGES / 256, 256, 0, stream>>>(ei, degc, N_EDGES);
        dinv_from_int_kernel<<<SCAN_NB, 256, 0, stream>>>(degc, dinv, N_NODES);

        hipMemsetAsync(agg, 0, fb2, stream);
        gemm64f_kernel<<<(N_NODES / 64) * 2, 256, 0, stream>>>(x, W1, dinv, hbuf);
        edge_scatter_kernel<<<(N_EDGES * 32) / 256, 256, 0, stream>>>(ei, dinv, hbuf, agg, N_EDGES);
        post_kernel<<<(N_NODES * 32) / 256, 256, 0, stream>>>(agg, hbuf, dinv, b1, N_NODES);

        gemm64f_kernel<<<(N_NODES / 64) * 2, 256, 0, stream>>>(agg, W2, dinv, hbuf);
        hipMemsetAsync(agg, 0, fb2, stream);
        edge_scatter_kernel<<<(N_EDGES * 32) / 256, 256, 0, stream>>>(ei, dinv, hbuf, agg, N_EDGES);
        post_kernel<<<(N_NODES * 32) / 256, 256, 0, stream>>>(agg, hbuf, dinv, b2, N_NODES);

        pool_fc_kernel<<<N_GRAPHS, 128, 0, stream>>>(agg, batch, Wfc, bfc, out, N_NODES);
    }
}

// Round 11
// 271.574 us; speedup vs baseline: 1.0290x; 1.0290x over previous
//
#include <hip/hip_runtime.h>
#include <hip/hip_fp16.h>

#define N_NODES 40000
#define N_EDGES 640000
#define NFEAT   128
#define N_GRAPHS 512
#define SCAN_NB 157        // ceil(40000/256)
#define NBKT    157        // col buckets of 256 cols
#define BKT_CAP 8192       // slots per bucket region (mean ~4076, safe)
#define BIN_BLK_EDGES 2048
#define NBLK_A ((N_EDGES + BIN_BLK_EDGES - 1) / BIN_BLK_EDGES)  // 313
#define EPAD_MAX (N_EDGES + 3 * N_NODES)   // worst-case padded CSR

// ===========================================================================
// Init: gcursor=0, gcnt=0, out=bfc, hbuf sentinel row=0
// ===========================================================================
__global__ void init_misc_kernel(int* __restrict__ gcursor, int* __restrict__ gcnt,
                                 float* __restrict__ out, const float* __restrict__ bfc,
                                 __half* __restrict__ hsent) {
    int t = threadIdx.x;
    if (t < NBKT) gcursor[t] = 0;
    float b = bfc[0];
    for (int i = t; i < N_GRAPHS; i += 256) { gcnt[i] = 0; out[i] = b; }
    if (t < NFEAT) hsent[t] = __float2half(0.0f);
}

__global__ void batch_hist_kernel(const int* __restrict__ batch, int* __restrict__ gcnt, int n) {
    int i = blockIdx.x * blockDim.x + threadIdx.x;
    if (i < n) atomicAdd(&gcnt[batch[i]], 1);
}

// ===========================================================================
// Pass A: bin edges into NBKT coarse buckets (col>>8), packed (collow<<16|row).
// ===========================================================================
__global__ __launch_bounds__(256) void bin_kernel(const int* __restrict__ ei,
                                                  int* __restrict__ gcursor,
                                                  unsigned int* __restrict__ binned) {
    __shared__ int lhist[NBKT];
    __shared__ int lbase[NBKT];
    const int t  = threadIdx.x;
    const int e0 = blockIdx.x * BIN_BLK_EDGES;

    if (t < NBKT) lhist[t] = 0;
    __syncthreads();

    int creg[BIN_BLK_EDGES / 256];
    #pragma unroll
    for (int i = 0; i < BIN_BLK_EDGES / 256; ++i) {
        int e = e0 + i * 256 + t;
        creg[i] = (e < N_EDGES) ? ei[N_EDGES + e] : -1;
        if (creg[i] >= 0) atomicAdd(&lhist[creg[i] >> 8], 1);
    }
    __syncthreads();

    if (t < NBKT) { lbase[t] = atomicAdd(&gcursor[t], lhist[t]); lhist[t] = 0; }
    __syncthreads();

    #pragma unroll
    for (int i = 0; i < BIN_BLK_EDGES / 256; ++i) {
        int c = creg[i];
        if (c >= 0) {
            int e = e0 + i * 256 + t;
            int r = ei[e];
            int bkt = c >> 8;
            int slot = atomicAdd(&lhist[bkt], 1);
            binned[(size_t)bkt * BKT_CAP + lbase[bkt] + slot] =
                (unsigned int)r | ((unsigned int)(c & 255) << 16);
        }
    }
}

// ===========================================================================
// Pass B: per-bucket col histogram -> dinv, local exclusive scan of padded
// degrees -> rowptr local offsets + bucket totals.
// ===========================================================================
__global__ __launch_bounds__(256) void bucket_hist_kernel(const unsigned int* __restrict__ binned,
                                                          const int* __restrict__ gcursor,
                                                          float* __restrict__ dinv,
                                                          int* __restrict__ rowptr,
                                                          int* __restrict__ bsums) {
    __shared__ int chist[256];
    __shared__ int scn[256];
    const int b = blockIdx.x, t = threadIdx.x;
    chist[t] = 0;
    __syncthreads();
    const int cnt = gcursor[b];
    const unsigned int* src = binned + (size_t)b * BKT_CAP;
    for (int i = t; i < cnt; i += 256) atomicAdd(&chist[src[i] >> 16], 1);
    __syncthreads();
    const int col = b * 256 + t;
    const int valid = (col < N_NODES);
    int d = chist[t];
    if (valid) dinv[col] = rsqrtf(1.0f + (float)d);
    int pd = valid ? ((d + 3) & ~3) : 0;
    scn[t] = pd;
    __syncthreads();
    for (int off = 1; off < 256; off <<= 1) {
        int add = (t >= off) ? scn[t - off] : 0;
        __syncthreads();
        scn[t] += add;
        __syncthreads();
    }
    if (valid) rowptr[col] = scn[t] - pd;   // local offset
    if (t == 255) bsums[b] = scn[255];      // bucket total
}

// 157-element exclusive scan of bucket totals; write rowptr[N] = grand total
__global__ void scan157_kernel(int* __restrict__ bsums, int* __restrict__ rowptr) {
    __shared__ int tmp[256];
    int t = threadIdx.x;
    int v = (t < NBKT) ? bsums[t] : 0;
    tmp[t] = v;
    __syncthreads();
    for (int off = 1; off < 256; off <<= 1) {
        int add = (t >= off) ? tmp[t - off] : 0;
        __syncthreads();
        tmp[t] += add;
        __syncthreads();
    }
    if (t < NBKT) bsums[t] = tmp[t] - v;
    if (t == 255) rowptr[N_NODES] = tmp[255];
}

// ===========================================================================
// Pass C: finalize rowptr (+base), scatter into CSR via LDS cursors, pads.
// ===========================================================================
template <typename IdxT>
__global__ __launch_bounds__(256) void bucket_scatter_kernel(const unsigned int* __restrict__ binned,
                                                             const int* __restrict__ gcursor,
                                                             const int* __restrict__ bsums,
                                                             int* __restrict__ rowptr,
                                                             IdxT* __restrict__ csr) {
    __shared__ int ccur[256];
    const int b = blockIdx.x, t = threadIdx.x;
    const int col = b * 256 + t;
    const int base = bsums[b];
    int startp = 0;
    if (col < N_NODES) {
        startp = rowptr[col] + base;
        rowptr[col] = startp;     // final
    }
    ccur[t] = startp;
    __syncthreads();
    const int cnt = gcursor[b];
    const unsigned int* src = binned + (size_t)b * BKT_CAP;
    for (int i = t; i < cnt; i += 256) {
        unsigned int u = src[i];
        int slot = atomicAdd(&ccur[u >> 16], 1);
        csr[slot] = (IdxT)(u & 0xFFFFu);
    }
    __syncthreads();
    if (col < N_NODES) {
        int cur = ccur[t];
        int deg = cur - startp;
        int endp = startp + ((deg + 3) & ~3);
        for (int p = cur; p < endp; ++p) csr[p] = (IdxT)N_NODES;
    }
}

// ===========================================================================
// fp16 load helper
// ===========================================================================
__device__ inline float4 load_h4(const __half* p) {
    uint2 raw = *(const uint2*)p;
    __half2 h0 = *(__half2*)&raw.x;
    __half2 h1 = *(__half2*)&raw.y;
    float2 f0 = __half22float2(h0);
    float2 f1 = __half22float2(h1);
    return make_float4(f0.x, f0.y, f1.x, f1.y);
}
__device__ inline float4 load4v(const float* p)  { return *(const float4*)(p); }
__device__ inline float4 load4v(const __half* p) { return load_h4(p); }

// ===========================================================================
// GEMM (r9-proven shape): Ht[r][c] = dinv[r] * sum_k X[r][k] * W[k][c]
// 256 threads -> 64 rows x 64 cols, thread = 4x4; W col-half (32 KB LDS)
// -> 4 blocks/CU; explicit X double-buffer prefetch. fp16 out.
// InT = float (layer 1, x) or __half (layer 2, fp16 obuf).
// ===========================================================================
template <typename InT>
__global__ __launch_bounds__(256, 4) void gemm64h_kernel(const InT* __restrict__ X,
                                                         const float* __restrict__ W,
                                                         const float* __restrict__ dinv,
                                                         __half* __restrict__ H) {
    __shared__ float Ws[128 * 64];
    const int colhalf = blockIdx.x & 1;
    const int tile    = blockIdx.x >> 1;

    for (int i = threadIdx.x; i < 2048; i += 256) {
        int k   = i >> 4;
        int cc4 = (i & 15) * 4;
        *(float4*)(Ws + k * 64 + cc4) = *(const float4*)(W + k * 128 + colhalf * 64 + cc4);
    }
    __syncthreads();

    const int rg = threadIdx.x >> 4;
    const int cg = threadIdx.x & 15;
    const int row0 = tile * 64 + rg * 4;
    const InT* x0 = X + (size_t)row0 * NFEAT;

    float acc[4][4] = {};
    float4 xc[4], xn[4];
    #pragma unroll
    for (int i = 0; i < 4; i++) xc[i] = load4v(x0 + (size_t)i * NFEAT);

    #pragma unroll 4
    for (int k = 0; k < 128; k += 4) {
        const int kn = (k + 4) & 127;
        #pragma unroll
        for (int i = 0; i < 4; i++) xn[i] = load4v(x0 + (size_t)i * NFEAT + kn);

        float4 wv[4];
        #pragma unroll
        for (int m = 0; m < 4; m++) wv[m] = *(const float4*)(Ws + (k + m) * 64 + cg * 4);

        #pragma unroll
        for (int i = 0; i < 4; i++) {
            const float xi[4] = {xc[i].x, xc[i].y, xc[i].z, xc[i].w};
            #pragma unroll
            for (int m = 0; m < 4; m++) {
                acc[i][0] += xi[m] * wv[m].x;
                acc[i][1] += xi[m] * wv[m].y;
                acc[i][2] += xi[m] * wv[m].z;
                acc[i][3] += xi[m] * wv[m].w;
            }
        }
        #pragma unroll
        for (int i = 0; i < 4; i++) xc[i] = xn[i];
    }

    #pragma unroll
    for (int i = 0; i < 4; i++) {
        float dr = dinv[row0 + i];
        __half2 p0 = __floats2half2_rn(acc[i][0] * dr, acc[i][1] * dr);
        __half2 p1 = __floats2half2_rn(acc[i][2] * dr, acc[i][3] * dr);
        uint2 pk;
        pk.x = *(unsigned int*)&p0;
        pk.y = *(unsigned int*)&p1;
        *(uint2*)(H + (size_t)(row0 + i) * NFEAT + colhalf * 64 + cg * 4) = pk;
    }
}

// ===========================================================================
// fp16 gather (r9 shape, idx prefetch): one wave per node; 8 B/lane;
// half-waves take alternating neighbors; padded CSR -> aligned 4-index loads,
// next idx vector prefetched. NO dynamic vector indexing (r8 LDS-spill trap).
// Layer 1: write fp16 outh. FUSE_POOL: dot Wfc, reduce, store nodedot[node].
// ===========================================================================
template <typename IdxT, typename IdxV, bool FUSE_POOL>
__global__ __launch_bounds__(256) void gather_h16_kernel(
        const int* __restrict__ rowptr, const IdxT* __restrict__ csr,
        const float* __restrict__ dinv, const __half* __restrict__ Ht,
        const float* __restrict__ bias, __half* __restrict__ outh,
        const float* __restrict__ Wfc, float* __restrict__ nodedot, int n) {
    int gid  = blockIdx.x * blockDim.x + threadIdx.x;
    int node = gid >> 6;
    if (node >= n) return;
    int lane = threadIdx.x & 63;
    int half = lane >> 5;
    int f4   = (lane & 31) * 4;

    int start = rowptr[node];
    int end   = rowptr[node + 1];

    float4 a0 = {0.f, 0.f, 0.f, 0.f};
    float4 a1 = {0.f, 0.f, 0.f, 0.f};
    if (half == 0) a0 = load_h4(Ht + (size_t)node * NFEAT + f4);  // self-loop

    IdxV nxt = *(const IdxV*)(csr + start);
    for (int j = start; j < end; j += 4) {
        IdxV cur = nxt;
        int jn = j + 4;
        if (jn < end) nxt = *(const IdxV*)(csr + jn);
        int r0 = half ? (int)cur.z : (int)cur.x;
        int r1 = half ? (int)cur.w : (int)cur.y;
        float4 v0 = load_h4(Ht + (size_t)r0 * NFEAT + f4);
        float4 v1 = load_h4(Ht + (size_t)r1 * NFEAT + f4);
        a0.x += v0.x; a0.y += v0.y; a0.z += v0.z; a0.w += v0.w;
        a1.x += v1.x; a1.y += v1.y; a1.z += v1.z; a1.w += v1.w;
    }
    a0.x += a1.x; a0.y += a1.y; a0.z += a1.z; a0.w += a1.w;

    a0.x += __shfl_xor(a0.x, 32, 64);
    a0.y += __shfl_xor(a0.y, 32, 64);
    a0.z += __shfl_xor(a0.z, 32, 64);
    a0.w += __shfl_xor(a0.w, 32, 64);

    if (half == 0) {
        float di  = dinv[node];
        float4 bb = *(const float4*)(bias + f4);
        float4 o;
        o.x = fmaxf(a0.x * di + bb.x, 0.0f);
        o.y = fmaxf(a0.y * di + bb.y, 0.0f);
        o.z = fmaxf(a0.z * di + bb.z, 0.0f);
        o.w = fmaxf(a0.w * di + bb.w, 0.0f);
        if (!FUSE_POOL) {
            __half2 p0 = __floats2half2_rn(o.x, o.y);
            __half2 p1 = __floats2half2_rn(o.z, o.w);
            uint2 pk;
            pk.x = *(unsigned int*)&p0;
            pk.y = *(unsigned int*)&p1;
            *(uint2*)(outh + (size_t)node * NFEAT + f4) = pk;
        } else {
            float4 wf = *(const float4*)(Wfc + f4);
            float d = o.x * wf.x + o.y * wf.y + o.z * wf.z + o.w * wf.w;
            d += __shfl_xor(d, 1, 64);
            d += __shfl_xor(d, 2, 64);
            d += __shfl_xor(d, 4, 64);
            d += __shfl_xor(d, 8, 64);
            d += __shfl_xor(d, 16, 64);
            if (lane == 0) nodedot[node] = d;   // wave owns node: plain store
        }
    }
}

// out[batch[i]] += nodedot[i] / cnt
__global__ void pool_final_kernel(const float* __restrict__ nodedot,
                                  const int* __restrict__ batch,
                                  const int* __restrict__ gcnt,
                                  float* __restrict__ out, int n) {
    int i = blockIdx.x * blockDim.x + threadIdx.x;
    if (i < n) {
        int g = batch[i];
        int c = gcnt[g];
        float cf = (float)(c > 0 ? c : 1);
        atomicAdd(&out[g], nodedot[i] / cf);
    }
}

// ===========================================================================
// Tier C fallback kernels (fp32, atomic scatter)
// ===========================================================================
__global__ void edge_deg_int_kernel(const int* __restrict__ ei, int* __restrict__ degcnt, int E) {
    int e = blockIdx.x * blockDim.x + threadIdx.x;
    if (e < E) atomicAdd(&degcnt[ei[E + e]], 1);
}

__global__ void dinv_from_int_kernel(const int* __restrict__ degcnt, float* __restrict__ dinv, int n) {
    int i = blockIdx.x * blockDim.x + threadIdx.x;
    if (i < n) dinv[i] = rsqrtf(1.0f + (float)degcnt[i]);
}

__global__ __launch_bounds__(256, 4) void gemm64f_kernel(const float* __restrict__ X,
                                                         const float* __restrict__ W,
                                                         const float* __restrict__ dinv,
                                                         float* __restrict__ H) {
    __shared__ float Ws[128 * 64];
    const int colhalf = blockIdx.x & 1;
    const int tile    = blockIdx.x >> 1;
    for (int i = threadIdx.x; i < 2048; i += 256) {
        int k   = i >> 4;
        int cc4 = (i & 15) * 4;
        *(float4*)(Ws + k * 64 + cc4) = *(const float4*)(W + k * 128 + colhalf * 64 + cc4);
    }
    __syncthreads();
    const int rg = threadIdx.x >> 4;
    const int cg = threadIdx.x & 15;
    const int row0 = tile * 64 + rg * 4;
    const float* x0 = X + (size_t)row0 * NFEAT;
    float acc[4][4] = {};
    #pragma unroll 4
    for (int k = 0; k < 128; k += 4) {
        float4 xv[4];
        float4 wv[4];
        #pragma unroll
        for (int i = 0; i < 4; i++) xv[i] = *(const float4*)(x0 + (size_t)i * NFEAT + k);
        #pragma unroll
        for (int m = 0; m < 4; m++) wv[m] = *(const float4*)(Ws + (k + m) * 64 + cg * 4);
        #pragma unroll
        for (int i = 0; i < 4; i++) {
            const float xi[4] = {xv[i].x, xv[i].y, xv[i].z, xv[i].w};
            #pragma unroll
            for (int m = 0; m < 4; m++) {
                acc[i][0] += xi[m] * wv[m].x;
                acc[i][1] += xi[m] * wv[m].y;
                acc[i][2] += xi[m] * wv[m].z;
                acc[i][3] += xi[m] * wv[m].w;
            }
        }
    }
    #pragma unroll
    for (int i = 0; i < 4; i++) {
        float dr = dinv[row0 + i];
        float4 o = {acc[i][0] * dr, acc[i][1] * dr, acc[i][2] * dr, acc[i][3] * dr};
        *(float4*)(H + (size_t)(row0 + i) * NFEAT + cg * 4 + colhalf * 64) = o;
    }
}

__global__ __launch_bounds__(256) void edge_scatter_kernel(const int* __restrict__ ei,
                                                           const float* __restrict__ dinv,
                                                           const float* __restrict__ H,
                                                           float* __restrict__ agg,
                                                           int E) {
    long long gid = (long long)blockIdx.x * blockDim.x + threadIdx.x;
    int e = (int)(gid >> 5);
    if (e >= E) return;
    int c4 = ((int)gid & 31) * 4;
    int r = ei[e];
    int c = ei[E + e];
    float norm = dinv[c];
    const float4 hv = *(const float4*)(H + (size_t)r * NFEAT + c4);
    float* dst = agg + (size_t)c * NFEAT + c4;
    atomicAdd(dst + 0, hv.x * norm);
    atomicAdd(dst + 1, hv.y * norm);
    atomicAdd(dst + 2, hv.z * norm);
    atomicAdd(dst + 3, hv.w * norm);
}

__global__ void post_kernel(float* __restrict__ agg, const float* __restrict__ H,
                            const float* __restrict__ dinv, const float* __restrict__ b,
                            int n) {
    int gid = blockIdx.x * blockDim.x + threadIdx.x;
    if (gid >= n * 32) return;
    int node = gid >> 5;
    int c4 = (gid & 31) * 4;
    float s = dinv[node];
    float4 a  = *(float4*)(agg + (size_t)gid * 4);
    float4 hv = *(const float4*)(H + (size_t)gid * 4);
    float4 bb = *(const float4*)(b + c4);
    float4 o;
    o.x = fmaxf(a.x + hv.x * s + bb.x, 0.0f);
    o.y = fmaxf(a.y + hv.y * s + bb.y, 0.0f);
    o.z = fmaxf(a.z + hv.z * s + bb.z, 0.0f);
    o.w = fmaxf(a.w + hv.w * s + bb.w, 0.0f);
    *(float4*)(agg + (size_t)gid * 4) = o;
}

__global__ __launch_bounds__(128) void pool_fc_kernel(const float* __restrict__ H,
                                                      const int* __restrict__ batch,
                                                      const float* __restrict__ Wfc,
                                                      const float* __restrict__ bfc,
                                                      float* __restrict__ out, int n) {
    int g = blockIdx.x;
    int tid = threadIdx.x;
    int lo = 0, hi = n;
    while (lo < hi) { int mid = (lo + hi) >> 1; if (batch[mid] < g) lo = mid + 1; else hi = mid; }
    int start = lo;
    hi = n;
    while (lo < hi) { int mid = (lo + hi) >> 1; if (batch[mid] < g + 1) lo = mid + 1; else hi = mid; }
    int end = lo;
    float acc = 0.0f;
    for (int nd = start; nd < end; ++nd) acc += H[(size_t)nd * NFEAT + tid];
    float cnt = (float)((end - start) > 0 ? (end - start) : 1);
    float v = (acc / cnt) * Wfc[tid];
    __shared__ float red[128];
    red[tid] = v;
    __syncthreads();
    #pragma unroll
    for (int s = 64; s > 0; s >>= 1) {
        if (tid < s) red[tid] += red[tid + s];
        __syncthreads();
    }
    if (tid == 0) out[g] = red[0] + bfc[0];
}

// ===========================================================================
// Host launcher — main path: ushort CSR, fp16 hbuf + fp16 obuf
// ===========================================================================
static void run_csr_path(const float* x, const int* ei, const int* batch,
                         const float* W1, const float* b1, const float* W2,
                         const float* b2, const float* Wfc, const float* bfc,
                         float* out, void* d_ws, hipStream_t stream) {
    typedef unsigned short IdxT;
    typedef ushort4 IdxV;
    char* ws = (char*)d_ws;
    const size_t hbytes = (size_t)(N_NODES + 1) * NFEAT * sizeof(__half);  // +1 sentinel row
    const size_t obytes = (size_t)N_NODES * NFEAT * sizeof(__half);
    __half* hbuf  = (__half*)ws;
    __half* obuf  = (__half*)(ws + hbytes);
    IdxT*   csr   = (IdxT*)(ws + hbytes + obytes);
    char*   p     = ws + hbytes + obytes + ((size_t)EPAD_MAX * sizeof(IdxT) + 15) / 16 * 16;
    int*    rowptr = (int*)p;                p += ((size_t)(N_NODES + 1) * 4 + 15) / 16 * 16;
    float*  dinv   = (float*)p;              p += ((size_t)N_NODES * 4 + 15) / 16 * 16;
    int*    gcnt   = (int*)p;                // 512 ints (live through pool_final)

    // CSR-build scratch overlapping obuf (dead until gather1 writes it)
    unsigned int* binned = (unsigned int*)obuf;        // NBKT*BKT_CAP u32 = 5.14 MB < 10.2 MB
    int* bsums   = (int*)obuf + NBKT * BKT_CAP;        // NBKT ints
    int* gcursor = bsums + NBKT;                       // NBKT ints
    // nodedot: separate region after gcnt (obuf head is fp16-written by gather1;
    // dead after gemm2, but keep nodedot disjoint for clarity)
    float* nodedot = (float*)(p + (((size_t)N_GRAPHS * 4 + 15) / 16 * 16));

    // ---- init + CSR build (binned counting sort, fused scans) ----
    init_misc_kernel<<<1, 256, 0, stream>>>(gcursor, gcnt, out, bfc,
                                            hbuf + (size_t)N_NODES * NFEAT);
    batch_hist_kernel<<<SCAN_NB, 256, 0, stream>>>(batch, gcnt, N_NODES);
    bin_kernel<<<NBLK_A, 256, 0, stream>>>(ei, gcursor, binned);
    bucket_hist_kernel<<<NBKT, 256, 0, stream>>>(binned, gcursor, dinv, rowptr, bsums);
    scan157_kernel<<<1, 256, 0, stream>>>(bsums, rowptr);
    bucket_scatter_kernel<IdxT><<<NBKT, 256, 0, stream>>>(binned, gcursor, bsums, rowptr, csr);

    // ---- layer 1 ----
    gemm64h_kernel<float><<<(N_NODES / 64) * 2, 256, 0, stream>>>(x, W1, dinv, hbuf);
    gather_h16_kernel<IdxT, IdxV, false><<<(N_NODES * 64) / 256, 256, 0, stream>>>(
        rowptr, csr, dinv, hbuf, b1, obuf, nullptr, nullptr, N_NODES);

    // ---- layer 2 ----
    gemm64h_kernel<__half><<<(N_NODES / 64) * 2, 256, 0, stream>>>(obuf, W2, dinv, hbuf);
    gather_h16_kernel<IdxT, IdxV, true><<<(N_NODES * 64) / 256, 256, 0, stream>>>(
        rowptr, csr, dinv, hbuf, b2, nullptr, Wfc, nodedot, N_NODES);

    // ---- final pool ----
    pool_final_kernel<<<SCAN_NB, 256, 0, stream>>>(nodedot, batch, gcnt, out, N_NODES);
}

extern "C" void kernel_launch(void* const* d_in, const int* in_sizes, int n_in,
                              void* d_out, int out_size, void* d_ws, size_t ws_size,
                              hipStream_t stream) {
    const float* x     = (const float*)d_in[0];
    const int*   ei    = (const int*)  d_in[1];
    const int*   batch = (const int*)  d_in[2];
    const float* W1    = (const float*)d_in[3];
    const float* b1    = (const float*)d_in[4];
    const float* W2    = (const float*)d_in[5];
    const float* b2    = (const float*)d_in[6];
    const float* Wfc   = (const float*)d_in[7];
    const float* bfc   = (const float*)d_in[8];
    float* out = (float*)d_out;

    const size_t hbytes = (size_t)(N_NODES + 1) * NFEAT * sizeof(__half);
    const size_t obytes = (size_t)N_NODES * NFEAT * sizeof(__half);
    const size_t tail   = ((size_t)(N_NODES + 1) * 4 + 15) / 16 * 16
                        + ((size_t)N_NODES * 4 + 15) / 16 * 16
                        + (((size_t)N_GRAPHS * 4 + 15) / 16 * 16)
                        + (size_t)N_NODES * 4;                       // nodedot
    const size_t need = hbytes + obytes + ((size_t)EPAD_MAX * 2 + 15) / 16 * 16 + tail;

    if (ws_size >= need) {
        run_csr_path(x, ei, batch, W1, b1, W2, b2, Wfc, bfc, out, d_ws, stream);
    } else {
        // Tier C: fp32 atomic-scatter fallback
        float* ws   = (float*)d_ws;
        int*   degc = (int*)ws;
        float* dinv = ws + N_NODES;
        float* hbuf = ws + 2 * N_NODES;
        float* agg  = hbuf + (size_t)N_NODES * NFEAT;
        const size_t fb2 = (size_t)N_NODES * NFEAT * sizeof(float);

        hipMemsetAsync(degc, 0, (size_t)N_NODES * sizeof(int), stream);
        edge_deg_int_kernel<<<N_EDGES / 256, 256, 0, stream>>>(ei, degc, N_EDGES);
        dinv_from_int_kernel<<<SCAN_NB, 256, 0, stream>>>(degc, dinv, N_NODES);

        hipMemsetAsync(agg, 0, fb2, stream);
        gemm64f_kernel<<<(N_NODES / 64) * 2, 256, 0, stream>>>(x, W1, dinv, hbuf);
        edge_scatter_kernel<<<(N_EDGES * 32) / 256, 256, 0, stream>>>(ei, dinv, hbuf, agg, N_EDGES);
        post_kernel<<<(N_NODES * 32) / 256, 256, 0, stream>>>(agg, hbuf, dinv, b1, N_NODES);

        gemm64f_kernel<<<(N_NODES / 64) * 2, 256, 0, stream>>>(agg, W2, dinv, hbuf);
        hipMemsetAsync(agg, 0, fb2, stream);
        edge_scatter_kernel<<<(N_EDGES * 32) / 256, 256, 0, stream>>>(ei, dinv, hbuf, agg, N_EDGES);
        post_kernel<<<(N_NODES * 32) / 256, 256, 0, stream>>>(agg, hbuf, dinv, b2, N_NODES);

        pool_fc_kernel<<<N_GRAPHS, 128, 0, stream>>>(agg, batch, Wfc, bfc, out, N_NODES);
    }
}